// Round 12
// baseline (586.984 us; speedup 1.0000x reference)
//
#include <hip/hip_runtime.h>

// Problem constants (fixed by setup_inputs)
#define D        256     // feature dim
#define NPG      512     // nodes per graph
#define BG       128     // num graphs
#define KSEL     256     // k = ceil(0.5 * 512)
#define EPG      4096    // edges per graph
#define NN       (BG * NPG)      // 65536 nodes
#define ET       (BG * EPG)      // 524288 edges

// ---------------------------------------------------------------------------
// Production pipeline: byte-identical to R7 (the 128.2 us best).
// ---------------------------------------------------------------------------

__global__ __launch_bounds__(256) void k_proj_scores(
        const float* __restrict__ x,
        const float* __restrict__ w_rel, const float* __restrict__ w_root,
        float* __restrict__ p, float* __restrict__ r) {
    int tid  = threadIdx.x;
    int wave = tid >> 6, lane = tid & 63;
    int node = blockIdx.x * 4 + wave;

    const float4* x4  = (const float4*)(x + (size_t)node * D);
    float4 xv = x4[lane];
    float4 wr = ((const float4*)w_rel)[lane];
    float4 wo = ((const float4*)w_root)[lane];
    float pv = xv.x * wr.x + xv.y * wr.y + xv.z * wr.z + xv.w * wr.w;
    float rv = xv.x * wo.x + xv.y * wo.y + xv.z * wo.z + xv.w * wo.w;
    #pragma unroll
    for (int off = 32; off; off >>= 1) {
        pv += __shfl_xor(pv, off, 64);
        rv += __shfl_xor(rv, off, 64);
    }
    if (lane == 0) { p[node] = pv; r[node] = rv; }
}

__global__ __launch_bounds__(1024) void k_select_pool(
        const float* __restrict__ x, const int* __restrict__ ei,
        const float* __restrict__ p, const float* __restrict__ r,
        const float* __restrict__ b_rel,
        float* __restrict__ ppart) {
    __shared__ __align__(16) float s_p[NPG];
    __shared__ __align__(16) float s_agg[NPG];
    __shared__ __align__(16) float s_val[NPG];
    __shared__ int   s_cnt4[1024];
    __shared__ int   s_selid[256];
    __shared__ __align__(16) float s_selv[256];
    __shared__ __align__(16) float s_red[16][D];
    __shared__ int   s_nsel;

    int blk = blockIdx.x;
    int b = blk >> 1, half = blk & 1;
    int tid = threadIdx.x, wave = tid >> 6, lane = tid & 63;
    int base = b * NPG;

    if (tid < NPG) { s_p[tid] = p[base + tid]; s_agg[tid] = 0.f; }
    if (tid == 0)  s_nsel = 0;
    __syncthreads();

    {
        const int* src = ei + (size_t)b * EPG;
        const int* dst = ei + ET + (size_t)b * EPG;
        #pragma unroll
        for (int e = tid; e < EPG; e += 1024)
            atomicAdd(&s_agg[dst[e] - base], s_p[src[e] - base]);
    }
    __syncthreads();

    if (tid < NPG)
        s_val[tid] = tanhf(s_agg[tid] + b_rel[0] + r[base + tid]);
    __syncthreads();

    {
        int j = half * 256 + (tid & 255);
        int q = tid >> 8;
        float sv = s_val[j];
        const float4* v4 = (const float4*)s_val + q * 32;
        int i0b = q * 128;
        int c = 0;
        #pragma unroll 8
        for (int t = 0; t < 32; ++t) {
            float4 o = v4[t];
            int i0 = i0b + t * 4;
            c += (o.x > sv) || (o.x == sv && (i0 + 0) < j);
            c += (o.y > sv) || (o.y == sv && (i0 + 1) < j);
            c += (o.z > sv) || (o.z == sv && (i0 + 2) < j);
            c += (o.w > sv) || (o.w == sv && (i0 + 3) < j);
        }
        s_cnt4[tid] = c;
    }
    __syncthreads();
    if (tid < 256) {
        int rank = s_cnt4[tid] + s_cnt4[tid + 256]
                 + s_cnt4[tid + 512] + s_cnt4[tid + 768];
        if (rank < KSEL) {
            int pos = atomicAdd(&s_nsel, 1);
            s_selid[pos] = half * 256 + tid;
            s_selv[pos]  = s_val[half * 256 + tid];
        }
    }
    __syncthreads();
    int nsel = s_nsel;

    {
        float4 acc = {0.f, 0.f, 0.f, 0.f};
        for (int s = wave; s < nsel; s += 16) {
            int row = s_selid[s];
            float v = s_selv[s];
            float4 xv = ((const float4*)(x + (size_t)(base + row) * D))[lane];
            acc.x += v * xv.x; acc.y += v * xv.y;
            acc.z += v * xv.z; acc.w += v * xv.w;
        }
        ((float4*)s_red[wave])[lane] = acc;
    }
    __syncthreads();

    if (tid < D) {
        float s = 0.f;
        #pragma unroll
        for (int w = 0; w < 16; ++w) s += s_red[w][tid];
        ppart[(size_t)blk * D + tid] = s;
    }
}

__global__ __launch_bounds__(1024) void k_project(
        const float* __restrict__ ppart,
        const float* __restrict__ w_proj, const float* __restrict__ b_proj,
        float* __restrict__ out) {
    __shared__ __align__(16) float s_pool[D];
    __shared__ __align__(16) float s_red[4][D];
    int b = blockIdx.x, tid = threadIdx.x;
    if (tid < D)
        s_pool[tid] = ppart[(size_t)(2 * b) * D + tid]
                    + ppart[(size_t)(2 * b + 1) * D + tid];
    __syncthreads();
    {
        int f = tid & (D - 1);
        int q = tid >> 8;
        const float4* pool4 = (const float4*)s_pool + q * 16;
        const float* wp = w_proj + (size_t)(q * 64) * D + f;
        float acc = 0.f;
        #pragma unroll
        for (int t = 0; t < 16; ++t) {
            float4 pv = pool4[t];
            acc += pv.x * wp[(t * 4 + 0) * D];
            acc += pv.y * wp[(t * 4 + 1) * D];
            acc += pv.z * wp[(t * 4 + 2) * D];
            acc += pv.w * wp[(t * 4 + 3) * D];
        }
        s_red[q][f] = acc;
    }
    __syncthreads();
    if (tid < D)
        out[(size_t)b * D + tid] = b_proj[tid] +
            (s_red[0][tid] + s_red[1][tid] + s_red[2][tid] + s_red[3][tid]) * (1.0f / KSEL);
}

// ---------------------------------------------------------------------------
// DIAGNOSTIC kernels — run AFTER the correct pipeline; write only private
// per-block ws regions (no races, no atomics, no DCE). 256-block / 1024-thr
// geometry matches the real K2. Phase cost = dur_us / REPEAT.
// ---------------------------------------------------------------------------
#define DIAG_SCATTER_R 24
#define DIAG_RANK_R    32
#define DIAG_GATHER_R  16
#define DIAG_BARRIER_R 96

// Phase: p-load + zero + edge scatter (LDS atomics).
__global__ __launch_bounds__(1024) void k_diag_scatter(
        const int* __restrict__ ei, const float* __restrict__ p,
        float* __restrict__ scratch) {
    __shared__ float s_p[NPG];
    __shared__ float s_agg[NPG];
    int blk = blockIdx.x, b = blk >> 1;
    int tid = threadIdx.x;
    int base = b * NPG;
    const int* src = ei + (size_t)b * EPG;
    const int* dst = ei + ET + (size_t)b * EPG;
    float chk = 0.f;
    for (int it = 0; it < DIAG_SCATTER_R; ++it) {
        if (tid < NPG) { s_p[tid] = p[base + tid]; s_agg[tid] = 0.f; }
        __syncthreads();
        #pragma unroll
        for (int e = tid; e < EPG; e += 1024)
            atomicAdd(&s_agg[dst[e] - base], s_p[src[e] - base]);
        __syncthreads();
        chk += s_agg[tid & (NPG - 1)];
        __syncthreads();
    }
    scratch[(size_t)blk * 1024 + tid] = chk;
}

// Phase: the O(N^2) rank. j rotates per iteration so the compare loop
// cannot be hoisted.
__global__ __launch_bounds__(1024) void k_diag_rank(
        const float* __restrict__ r, float* __restrict__ scratch) {
    __shared__ __align__(16) float s_val[NPG];
    __shared__ int s_cnt4[1024];
    int blk = blockIdx.x, b = blk >> 1, half = blk & 1;
    int tid = threadIdx.x;
    int base = b * NPG;
    if (tid < NPG) s_val[tid] = r[base + tid];
    __syncthreads();
    int chk = 0;
    for (int it = 0; it < DIAG_RANK_R; ++it) {
        int j = half * 256 + ((tid + it) & 255);
        int q = tid >> 8;
        float sv = s_val[j];
        const float4* v4 = (const float4*)s_val + q * 32;
        int i0b = q * 128;
        int c = 0;
        #pragma unroll 8
        for (int t = 0; t < 32; ++t) {
            float4 o = v4[t];
            int i0 = i0b + t * 4;
            c += (o.x > sv) || (o.x == sv && (i0 + 0) < j);
            c += (o.y > sv) || (o.y == sv && (i0 + 1) < j);
            c += (o.z > sv) || (o.z == sv && (i0 + 2) < j);
            c += (o.w > sv) || (o.w == sv && (i0 + 3) < j);
        }
        s_cnt4[tid] = c;
        __syncthreads();
        chk += s_cnt4[(tid + it) & 1023];
        __syncthreads();
    }
    scratch[(size_t)blk * 1024 + tid] = (float)chk;
}

// Phase: the selected-row weighted gather. Rows shift per iteration
// (rotating within the graph slice) so loads cannot be hoisted; access
// pattern (wave-uniform row, 1KB contiguous per wave) matches production.
// KEY READ: FETCH_SIZE of this dispatch tells us whether the gather is
// served by L3 (FETCH ~ 0) or misses to HBM (FETCH ~ 32 MB x R).
__global__ __launch_bounds__(1024) void k_diag_gather(
        const float* __restrict__ x, float* __restrict__ scratch) {
    __shared__ int s_selid[128];
    __shared__ float s_selv[128];
    int blk = blockIdx.x, b = blk >> 1;
    int tid = threadIdx.x, wave = tid >> 6, lane = tid & 63;
    int base = b * NPG;
    if (tid < 128) {
        s_selid[tid] = (tid * 37 + blk * 13) & (NPG - 1);  // pseudo-random rows
        s_selv[tid]  = 1.0f + tid * 0.01f;
    }
    __syncthreads();
    float4 acc = {0.f, 0.f, 0.f, 0.f};
    for (int it = 0; it < DIAG_GATHER_R; ++it) {
        for (int s = wave; s < 128; s += 16) {
            int row = (s_selid[s] + it * 101) & (NPG - 1);  // wave-uniform
            float v = s_selv[s];
            float4 xv = ((const float4*)(x + (size_t)(base + row) * D))[lane];
            acc.x += v * xv.x; acc.y += v * xv.y;
            acc.z += v * xv.z; acc.w += v * xv.w;
        }
    }
    float4* o4 = (float4*)(scratch + (size_t)blk * 1024);
    o4[tid] = acc;   // 1024 thr x 16 B = 16 KB/block region
}

// Phase skeleton: barrier/drain cost only (7 write-sync-read-sync pairs
// per iteration, trivial LDS work between).
__global__ __launch_bounds__(1024) void k_diag_barrier(
        float* __restrict__ scratch) {
    __shared__ float s_tmp[1024];
    int tid = threadIdx.x;
    float chk = 0.f;
    for (int it = 0; it < DIAG_BARRIER_R; ++it) {
        #pragma unroll
        for (int ph = 0; ph < 7; ++ph) {
            s_tmp[tid] = chk + ph;
            __syncthreads();
            chk += s_tmp[(tid + 64 * ph + it) & 1023];
            __syncthreads();
        }
    }
    scratch[(size_t)blockIdx.x * 1024 + tid] = chk;
}

extern "C" void kernel_launch(void* const* d_in, const int* in_sizes, int n_in,
                              void* d_out, int out_size, void* d_ws, size_t ws_size,
                              hipStream_t stream) {
    const float* x      = (const float*)d_in[0];
    const int*   ei     = (const int*)d_in[1];
    const float* w_rel  = (const float*)d_in[4];
    const float* b_rel  = (const float*)d_in[5];
    const float* w_root = (const float*)d_in[6];
    const float* w_proj = (const float*)d_in[7];
    const float* b_proj = (const float*)d_in[8];
    float* out = (float*)d_out;

    float* p     = (float*)d_ws;                 // NN floats
    float* r     = p + NN;                       // NN floats
    float* ppart = r + NN;                       // 2*BG*D floats
    // Private diag regions: 512 blocks x 1024 floats = 2 MB each (ws >= 256 MB)
    float* scr0  = ppart + (size_t)2 * BG * D;                 // scatter
    float* scr1  = scr0 + (size_t)512 * 1024;                  // rank
    float* scr2  = scr1 + (size_t)512 * 1024;                  // gather (4 KB/thr x4)
    float* scr3  = scr2 + (size_t)512 * 1024 * 4;              // barrier

    // Correct pipeline first (output identical to R7).
    k_proj_scores<<<NN / 4, 256, 0, stream>>>(x, w_rel, w_root, p, r);
    k_select_pool<<<2 * BG, 1024, 0, stream>>>(x, ei, p, r, b_rel, ppart);
    k_project<<<BG, 1024, 0, stream>>>(ppart, w_proj, b_proj, out);

    // Diagnostics (sacrificial; each crests the 41-us fill line).
    k_diag_scatter<<<2 * BG, 1024, 0, stream>>>(ei, p, scr0);
    k_diag_rank<<<2 * BG, 1024, 0, stream>>>(r, scr1);
    k_diag_gather<<<2 * BG, 1024, 0, stream>>>(x, scr2);
    k_diag_barrier<<<2 * BG, 1024, 0, stream>>>(scr3);
}

// Round 13
// 133.653 us; speedup vs baseline: 4.3919x; 4.3919x over previous
//
#include <hip/hip_runtime.h>

// Problem constants (fixed by setup_inputs)
#define D        256     // feature dim
#define NPG      512     // nodes per graph
#define BG       128     // num graphs
#define KSEL     256     // k = ceil(0.5 * 512)
#define EPG      4096    // edges per graph
#define NN       (BG * NPG)      // 65536 nodes
#define ET       (BG * EPG)      // 524288 edges

// Kernel A: p = x @ w_rel, r = x @ w_root (one wave per node).
// Full-chip stream of the 64 MB x — BW-bound, ~11 us (roofline).
__global__ __launch_bounds__(256) void k_proj_scores(
        const float* __restrict__ x,
        const float* __restrict__ w_rel, const float* __restrict__ w_root,
        float* __restrict__ p, float* __restrict__ r) {
    int tid  = threadIdx.x;
    int wave = tid >> 6, lane = tid & 63;
    int node = blockIdx.x * 4 + wave;

    const float4* x4  = (const float4*)(x + (size_t)node * D);
    float4 xv = x4[lane];
    float4 wr = ((const float4*)w_rel)[lane];
    float4 wo = ((const float4*)w_root)[lane];
    float pv = xv.x * wr.x + xv.y * wr.y + xv.z * wr.z + xv.w * wr.w;
    float rv = xv.x * wo.x + xv.y * wo.y + xv.z * wo.z + xv.w * wo.w;
    #pragma unroll
    for (int off = 32; off; off >>= 1) {
        pv += __shfl_xor(pv, off, 64);
        rv += __shfl_xor(rv, off, 64);
    }
    if (lane == 0) { p[node] = pv; r[node] = rv; }
}

// Monotonic float -> sortable uint (ascending uint == ascending float).
__device__ inline unsigned sortkey(float s) {
    unsigned u = __float_as_uint(s);
    return u ^ (unsigned)(((int)u >> 31) | 0x80000000);
}

// Kernel B: TWO blocks per graph (256 blocks, full chip).
// R12 diagnosis: the O(N^2) rank was 5.5 us/block (VALUBusy 79%) — replaced
// with an O(N) radix-histogram select on PRE-tanh scores (monotonic; ties
// at tanh saturation are far from the k-cut). tanh only for selected nodes.
// Everything else identical to R7 (the 128.2 us best).
__global__ __launch_bounds__(1024) void k_select_pool(
        const float* __restrict__ x, const int* __restrict__ ei,
        const float* __restrict__ p, const float* __restrict__ r,
        const float* __restrict__ b_rel,
        float* __restrict__ ppart) {
    __shared__ __align__(16) float s_p[NPG];
    __shared__ __align__(16) float s_agg[NPG];
    __shared__ __align__(16) float s_val[NPG];      // PRE-tanh scores
    __shared__ unsigned s_key[NPG];                 // sortable keys
    __shared__ int      s_sel[NPG];                 // selection flags
    __shared__ int      s_hist[256];                // top-8-bit histogram
    __shared__ unsigned s_candkey[NPG];             // crossing-bin members
    __shared__ int      s_candidx[NPG];
    __shared__ int      s_selid[256];
    __shared__ __align__(16) float s_selv[256];
    __shared__ __align__(16) float s_red[16][D];
    __shared__ int s_nsel, s_ncand, s_B, s_m;

    int blk = blockIdx.x;
    int b = blk >> 1, half = blk & 1;
    int tid = threadIdx.x, wave = tid >> 6, lane = tid & 63;
    int base = b * NPG;

    // ---- Init: threads <512 load p/zero agg; threads >=512 zero flags/hist.
    if (tid < NPG) { s_p[tid] = p[base + tid]; s_agg[tid] = 0.f; }
    else {
        int j = tid - NPG;
        s_sel[j] = 0;
        if (j < 256) s_hist[j] = 0;
    }
    if (tid == 0) { s_nsel = 0; s_ncand = 0; }
    __syncthreads();

    // ---- Edge scatter (duplicated per half-block): agg[dst] += p[src]
    {
        const int* src = ei + (size_t)b * EPG;
        const int* dst = ei + ET + (size_t)b * EPG;
        #pragma unroll
        for (int e = tid; e < EPG; e += 1024)
            atomicAdd(&s_agg[dst[e] - base], s_p[src[e] - base]);
    }
    __syncthreads();

    // ---- PRE-tanh score, sortable key, histogram (one pass).
    if (tid < NPG) {
        float s = s_agg[tid] + b_rel[0] + r[base + tid];
        s_val[tid] = s;
        unsigned k = sortkey(s);
        s_key[tid] = k;
        atomicAdd(&s_hist[k >> 24], 1);
    }
    __syncthreads();

    // ---- Wave 0: suffix-scan the histogram from the top, find crossing
    // bin B with cnt_above(B) < KSEL <= cnt_above(B) + hist[B].
    if (wave == 0) {
        int c0 = s_hist[4 * lane + 0], c1 = s_hist[4 * lane + 1];
        int c2 = s_hist[4 * lane + 2], c3 = s_hist[4 * lane + 3];
        int lsum = c0 + c1 + c2 + c3;
        int suf = lsum;                       // will become sum over lanes >= me
        #pragma unroll
        for (int off = 1; off < 64; off <<= 1) {
            int v = __shfl_down(suf, off, 64);
            if (lane + off < 64) suf += v;
        }
        int above = suf - lsum;               // count in bins > 4*lane+3
        int a3 = above, a2 = a3 + c3, a1 = a2 + c2, a0 = a1 + c1;
        if (a3 < KSEL && KSEL <= a3 + c3) { s_B = 4 * lane + 3; s_m = a3; }
        if (a2 < KSEL && KSEL <= a2 + c2) { s_B = 4 * lane + 2; s_m = a2; }
        if (a1 < KSEL && KSEL <= a1 + c1) { s_B = 4 * lane + 1; s_m = a1; }
        if (a0 < KSEL && KSEL <= a0 + c0) { s_B = 4 * lane + 0; s_m = a0; }
    }
    __syncthreads();
    int B = s_B, kk = KSEL - s_m;             // need kk more from bin B

    // ---- Mark sure-selected; ballot-compact crossing-bin candidates.
    {
        int cand = 0;
        if (tid < NPG) {
            int bin = s_key[tid] >> 24;
            if (bin > B) s_sel[tid] = 1;
            cand = (bin == B);
        }
        unsigned long long mball = __ballot(cand);
        if (mball) {
            int wbase = 0;
            if (lane == 0) wbase = atomicAdd(&s_ncand, __popcll(mball));
            wbase = __shfl(wbase, 0, 64);
            if (cand) {
                int pos = wbase + __popcll(mball & ((1ull << lane) - 1ull));
                s_candkey[pos] = s_key[tid];
                s_candidx[pos] = tid;
            }
        }
    }
    __syncthreads();
    int ncand = s_ncand;                      // kk <= ncand (by construction)

    // ---- Exact rank among candidates only (key desc, index asc).
    // Typical ncand ~ 5-15 -> tiny broadcast loop; worst case still correct.
    if (tid < ncand) {
        unsigned mykey = s_candkey[tid];
        int myidx = s_candidx[tid];
        int rnk = 0;
        for (int i = 0; i < ncand; ++i) {
            unsigned ok = s_candkey[i];       // broadcast LDS read
            rnk += (ok > mykey) || (ok == mykey && s_candidx[i] < myidx);
        }
        if (rnk < kk) s_sel[myidx] = 1;
    }
    __syncthreads();

    // ---- Compact MY half's selected nodes; tanh only for selected.
    if (tid < 256) {
        int node = half * 256 + tid;
        int sel = s_sel[node];
        unsigned long long mball = __ballot(sel);
        if (mball) {
            int wbase = 0;
            if (lane == 0) wbase = atomicAdd(&s_nsel, __popcll(mball));
            wbase = __shfl(wbase, 0, 64);
            if (sel) {
                int pos = wbase + __popcll(mball & ((1ull << lane) - 1ull));
                s_selid[pos] = node;
                s_selv[pos]  = tanhf(s_val[node]);
            }
        }
    }
    __syncthreads();
    int nsel = s_nsel;                        // halves sum to KSEL

    // ---- Weighted pool over MY selected rows (L3-warm gather).
    {
        float4 acc = {0.f, 0.f, 0.f, 0.f};
        for (int s = wave; s < nsel; s += 16) {
            int row = s_selid[s];             // wave-uniform broadcast
            float v = s_selv[s];
            float4 xv = ((const float4*)(x + (size_t)(base + row) * D))[lane];
            acc.x += v * xv.x; acc.y += v * xv.y;
            acc.z += v * xv.z; acc.w += v * xv.w;
        }
        ((float4*)s_red[wave])[lane] = acc;
    }
    __syncthreads();

    // ---- Write RAW pooled partial (no matvec here — R7's measured win).
    if (tid < D) {
        float s = 0.f;
        #pragma unroll
        for (int w = 0; w < 16; ++w) s += s_red[w][tid];
        ppart[(size_t)blk * D + tid] = s;
    }
}

// Kernel C: pool[b] = ppart[2b] + ppart[2b+1];
// out[b,f] = b_proj[f] + (1/k) * sum_kk pool[kk] * w_proj[kk,f].
__global__ __launch_bounds__(1024) void k_project(
        const float* __restrict__ ppart,
        const float* __restrict__ w_proj, const float* __restrict__ b_proj,
        float* __restrict__ out) {
    __shared__ __align__(16) float s_pool[D];
    __shared__ __align__(16) float s_red[4][D];
    int b = blockIdx.x, tid = threadIdx.x;
    if (tid < D)
        s_pool[tid] = ppart[(size_t)(2 * b) * D + tid]
                    + ppart[(size_t)(2 * b + 1) * D + tid];
    __syncthreads();
    {
        int f = tid & (D - 1);
        int q = tid >> 8;
        const float4* pool4 = (const float4*)s_pool + q * 16;
        const float* wp = w_proj + (size_t)(q * 64) * D + f;
        float acc = 0.f;
        #pragma unroll
        for (int t = 0; t < 16; ++t) {
            float4 pv = pool4[t];
            acc += pv.x * wp[(t * 4 + 0) * D];
            acc += pv.y * wp[(t * 4 + 1) * D];
            acc += pv.z * wp[(t * 4 + 2) * D];
            acc += pv.w * wp[(t * 4 + 3) * D];
        }
        s_red[q][f] = acc;
    }
    __syncthreads();
    if (tid < D)
        out[(size_t)b * D + tid] = b_proj[tid] +
            (s_red[0][tid] + s_red[1][tid] + s_red[2][tid] + s_red[3][tid]) * (1.0f / KSEL);
}

extern "C" void kernel_launch(void* const* d_in, const int* in_sizes, int n_in,
                              void* d_out, int out_size, void* d_ws, size_t ws_size,
                              hipStream_t stream) {
    const float* x      = (const float*)d_in[0];
    const int*   ei     = (const int*)d_in[1];
    // d_in[2] = batch (unused: contiguous equal-size graphs)
    // d_in[3] = num_graphs (hardcoded BG)
    const float* w_rel  = (const float*)d_in[4];
    const float* b_rel  = (const float*)d_in[5];
    const float* w_root = (const float*)d_in[6];
    const float* w_proj = (const float*)d_in[7];
    const float* b_proj = (const float*)d_in[8];
    float* out = (float*)d_out;

    float* p     = (float*)d_ws;                 // NN floats
    float* r     = p + NN;                       // NN floats
    float* ppart = r + NN;                       // 2*BG*D floats

    k_proj_scores<<<NN / 4, 256, 0, stream>>>(x, w_rel, w_root, p, r);
    k_select_pool<<<2 * BG, 1024, 0, stream>>>(x, ei, p, r, b_rel, ppart);
    k_project<<<BG, 1024, 0, stream>>>(ppart, w_proj, b_proj, out);
}

// Round 14
// 128.408 us; speedup vs baseline: 4.5713x; 1.0408x over previous
//
#include <hip/hip_runtime.h>

// Problem constants (fixed by setup_inputs)
#define D        256     // feature dim
#define NPG      512     // nodes per graph
#define BG       128     // num graphs
#define KSEL     256     // k = ceil(0.5 * 512)
#define EPG      4096    // edges per graph
#define NN       (BG * NPG)      // 65536 nodes
#define ET       (BG * EPG)      // 524288 edges

// Kernel A: p = x @ w_rel, r = x @ w_root (one wave per node).
// Full-chip stream of the 64 MB x — BW-bound, ~11 us (roofline).
__global__ __launch_bounds__(256) void k_proj_scores(
        const float* __restrict__ x,
        const float* __restrict__ w_rel, const float* __restrict__ w_root,
        float* __restrict__ p, float* __restrict__ r) {
    int tid  = threadIdx.x;
    int wave = tid >> 6, lane = tid & 63;
    int node = blockIdx.x * 4 + wave;

    const float4* x4  = (const float4*)(x + (size_t)node * D);
    float4 xv = x4[lane];
    float4 wr = ((const float4*)w_rel)[lane];
    float4 wo = ((const float4*)w_root)[lane];
    float pv = xv.x * wr.x + xv.y * wr.y + xv.z * wr.z + xv.w * wr.w;
    float rv = xv.x * wo.x + xv.y * wo.y + xv.z * wo.z + xv.w * wo.w;
    #pragma unroll
    for (int off = 32; off; off >>= 1) {
        pv += __shfl_xor(pv, off, 64);
        rv += __shfl_xor(rv, off, 64);
    }
    if (lane == 0) { p[node] = pv; r[node] = rv; }
}

// Kernel B: TWO blocks per graph (256 blocks, full chip). Each half-block
// duplicates the cheap whole-graph phases (p-load, edge scatter, tanh) and
// splits the expensive ones: ranks its 256 nodes, pools its own selected
// rows (~128, L3-warm), writes the RAW pooled partial. The O(N^2) rank is
// KEPT deliberately: it overlaps co-resident blocks' memory phases (R12/R13
// measured), while all "cheaper" selects lengthened the barrier chain.
__global__ __launch_bounds__(1024) void k_select_pool(
        const float* __restrict__ x, const int* __restrict__ ei,
        const float* __restrict__ p, const float* __restrict__ r,
        const float* __restrict__ b_rel,
        float* __restrict__ ppart) {
    __shared__ __align__(16) float s_p[NPG];
    __shared__ __align__(16) float s_agg[NPG];
    __shared__ __align__(16) float s_val[NPG];
    __shared__ int   s_cnt4[1024];
    __shared__ int   s_selid[256];
    __shared__ __align__(16) float s_selv[256];
    __shared__ __align__(16) float s_red[16][D];
    __shared__ int   s_nsel;

    int blk = blockIdx.x;
    int b = blk >> 1, half = blk & 1;
    int tid = threadIdx.x, wave = tid >> 6, lane = tid & 63;
    int base = b * NPG;

    if (tid < NPG) { s_p[tid] = p[base + tid]; s_agg[tid] = 0.f; }
    if (tid == 0)  s_nsel = 0;
    __syncthreads();

    // ---- Edge scatter (duplicated per half-block): agg[dst] += p[src]
    {
        const int* src = ei + (size_t)b * EPG;
        const int* dst = ei + ET + (size_t)b * EPG;
        #pragma unroll
        for (int e = tid; e < EPG; e += 1024)
            atomicAdd(&s_agg[dst[e] - base], s_p[src[e] - base]);
    }
    __syncthreads();

    // ---- score = tanh(agg + b_rel + r)
    if (tid < NPG)
        s_val[tid] = tanhf(s_agg[tid] + b_rel[0] + r[base + tid]);
    __syncthreads();

    // ---- Exact rank for MY 256 nodes: 4 threads/node, 128 scores each.
    // rank(j) = #{i : s_i > s_j or (s_i == s_j and i < j)}
    {
        int j = half * 256 + (tid & 255);
        int q = tid >> 8;
        float sv = s_val[j];
        const float4* v4 = (const float4*)s_val + q * 32;
        int i0b = q * 128;
        int c = 0;
        #pragma unroll 8
        for (int t = 0; t < 32; ++t) {
            float4 o = v4[t];                // wave-uniform b128 broadcast
            int i0 = i0b + t * 4;
            c += (o.x > sv) || (o.x == sv && (i0 + 0) < j);
            c += (o.y > sv) || (o.y == sv && (i0 + 1) < j);
            c += (o.z > sv) || (o.z == sv && (i0 + 2) < j);
            c += (o.w > sv) || (o.w == sv && (i0 + 3) < j);
        }
        s_cnt4[tid] = c;
    }
    __syncthreads();
    if (tid < 256) {
        int rank = s_cnt4[tid] + s_cnt4[tid + 256]
                 + s_cnt4[tid + 512] + s_cnt4[tid + 768];
        if (rank < KSEL) {                   // top-KSEL overall (total order)
            int pos = atomicAdd(&s_nsel, 1);
            s_selid[pos] = half * 256 + tid;
            s_selv[pos]  = s_val[half * 256 + tid];
        }
    }
    __syncthreads();
    int nsel = s_nsel;                       // halves sum to KSEL

    // ---- Weighted pool over MY selected rows (L3-warm gather).
    {
        float4 acc = {0.f, 0.f, 0.f, 0.f};
        for (int s = wave; s < nsel; s += 16) {
            int row = s_selid[s];            // wave-uniform broadcast
            float v = s_selv[s];
            float4 xv = ((const float4*)(x + (size_t)(base + row) * D))[lane];
            acc.x += v * xv.x; acc.y += v * xv.y;
            acc.z += v * xv.z; acc.w += v * xv.w;
        }
        ((float4*)s_red[wave])[lane] = acc;
    }
    __syncthreads();

    // ---- Write RAW pooled partial (no matvec here — R7's measured win).
    if (tid < D) {
        float s = 0.f;
        #pragma unroll
        for (int w = 0; w < 16; ++w) s += s_red[w][tid];
        ppart[(size_t)blk * D + tid] = s;
    }
}

// Kernel C: pool[b] = ppart[2b] + ppart[2b+1];
// out[b,f] = b_proj[f] + (1/k) * sum_kk pool[kk] * w_proj[kk,f].
__global__ __launch_bounds__(1024) void k_project(
        const float* __restrict__ ppart,
        const float* __restrict__ w_proj, const float* __restrict__ b_proj,
        float* __restrict__ out) {
    __shared__ __align__(16) float s_pool[D];
    __shared__ __align__(16) float s_red[4][D];
    int b = blockIdx.x, tid = threadIdx.x;
    if (tid < D)
        s_pool[tid] = ppart[(size_t)(2 * b) * D + tid]
                    + ppart[(size_t)(2 * b + 1) * D + tid];
    __syncthreads();
    {
        int f = tid & (D - 1);
        int q = tid >> 8;
        const float4* pool4 = (const float4*)s_pool + q * 16;
        const float* wp = w_proj + (size_t)(q * 64) * D + f;
        float acc = 0.f;
        #pragma unroll
        for (int t = 0; t < 16; ++t) {
            float4 pv = pool4[t];
            acc += pv.x * wp[(t * 4 + 0) * D];
            acc += pv.y * wp[(t * 4 + 1) * D];
            acc += pv.z * wp[(t * 4 + 2) * D];
            acc += pv.w * wp[(t * 4 + 3) * D];
        }
        s_red[q][f] = acc;
    }
    __syncthreads();
    if (tid < D)
        out[(size_t)b * D + tid] = b_proj[tid] +
            (s_red[0][tid] + s_red[1][tid] + s_red[2][tid] + s_red[3][tid]) * (1.0f / KSEL);
}

extern "C" void kernel_launch(void* const* d_in, const int* in_sizes, int n_in,
                              void* d_out, int out_size, void* d_ws, size_t ws_size,
                              hipStream_t stream) {
    const float* x      = (const float*)d_in[0];
    const int*   ei     = (const int*)d_in[1];
    // d_in[2] = batch (unused: contiguous equal-size graphs)
    // d_in[3] = num_graphs (hardcoded BG)
    const float* w_rel  = (const float*)d_in[4];
    const float* b_rel  = (const float*)d_in[5];
    const float* w_root = (const float*)d_in[6];
    const float* w_proj = (const float*)d_in[7];
    const float* b_proj = (const float*)d_in[8];
    float* out = (float*)d_out;

    float* p     = (float*)d_ws;                 // NN floats
    float* r     = p + NN;                       // NN floats
    float* ppart = r + NN;                       // 2*BG*D floats

    k_proj_scores<<<NN / 4, 256, 0, stream>>>(x, w_rel, w_root, p, r);
    k_select_pool<<<2 * BG, 1024, 0, stream>>>(x, ei, p, r, b_rel, ppart);
    k_project<<<BG, 1024, 0, stream>>>(ppart, w_proj, b_proj, out);
}